// Round 4
// baseline (250.622 us; speedup 1.0000x reference)
//
#include <hip/hip_runtime.h>
#include <hip/hip_cooperative_groups.h>
#include <climits>

#define EMB 128
#define EMB2 256
#define GRID_BLOCKS 1024
#define BLOCK_THREADS 256

typedef float v4f __attribute__((ext_vector_type(4)));
typedef int   v4i __attribute__((ext_vector_type(4)));

// ---------------------------------------------------------------------------
// Kernel 1 (tiny): weff[k] = sum_j Wo[0,128+j] * Wq[j,k], k in [0,256)
// ---------------------------------------------------------------------------
__global__ void weff_kernel(const float* __restrict__ Wq,
                            const float* __restrict__ Wo,
                            float* __restrict__ weff) {
    int k = threadIdx.x;  // 256 threads
    float acc = 0.f;
#pragma unroll 8
    for (int j = 0; j < EMB; ++j)
        acc += Wo[EMB + j] * Wq[j * EMB2 + k];
    weff[k] = acc;
}

// ---------------------------------------------------------------------------
// Kernel 2 (cooperative, 1024 blocks x 256 threads):
//  phase 1a: per-block min of max(ei0,ei1) -> slots[blockIdx]   (no atomics)
//  phase 1b: node dot table tab[i] = {Wo1.z[i], weffA.z[i], weffB.z0[i], 0}
//            (2 rows/wave, float4 NT loads, 5-stage xor-shuffle reduce)
//  grid.sync()
//  phase 2a: every block reduces slots[1024] -> qmin (LDS broadcast)
//  phase 2b: out[e] = tab[a].x + tab[b].y + tab[max(a,b)-qmin].z + bo
//            (same grid-stride as 1a -> per-XCD L2 re-hits on ei)
// ---------------------------------------------------------------------------
__global__ void fused_kernel(const float* __restrict__ z,
                             const float* __restrict__ z0,
                             const int* __restrict__ ei, int E,
                             const float* __restrict__ Wo,
                             const float* __restrict__ weff,
                             const float* __restrict__ bo,
                             v4f* __restrict__ tab, int N,
                             int* __restrict__ slots,
                             float* __restrict__ out) {
    cooperative_groups::grid_group grid = cooperative_groups::this_grid();
    const int gtid = blockIdx.x * BLOCK_THREADS + threadIdx.x;
    const int ntot = GRID_BLOCKS * BLOCK_THREADS;
    const int nvec = E >> 2;
    const v4i* r0 = (const v4i*)ei;
    const v4i* r1 = (const v4i*)(ei + E);

    // ---- phase 1a: qmin partial ----
    int m = INT_MAX;
    for (int v = gtid; v < nvec; v += ntot) {
        v4i a = r0[v];
        v4i b = r1[v];
        int m0 = max(a.x, b.x), m1 = max(a.y, b.y);
        int m2 = max(a.z, b.z), m3 = max(a.w, b.w);
        m = min(m, min(min(m0, m1), min(m2, m3)));
    }
    if (gtid < (E & 3)) {  // tail edges
        int e = (nvec << 2) + gtid;
        m = min(m, max(ei[e], ei[e + E]));
    }
#pragma unroll
    for (int off = 32; off; off >>= 1)
        m = min(m, __shfl_xor(m, off, 64));
    __shared__ int sm[4];
    if ((threadIdx.x & 63) == 0) sm[threadIdx.x >> 6] = m;
    __syncthreads();
    if (threadIdx.x == 0)
        slots[blockIdx.x] = min(min(sm[0], sm[1]), min(sm[2], sm[3]));

    // ---- phase 1b: node dots ----
    {
        int wave = gtid >> 6, lane = gtid & 63;
        int nwaves = ntot >> 6;
        int sub = lane >> 5;  // row within pair
        int c = lane & 31;    // float4 column group
        v4f w1 = ((const v4f*)Wo)[c];
        v4f wa = ((const v4f*)weff)[c];
        v4f wb = ((const v4f*)weff)[32 + c];
        int npairs = (N + 1) >> 1;
        for (int p = wave; p < npairs; p += nwaves) {
            int row = 2 * p + sub;
            v4f zv, z0v;
            if (row < N) {
                zv  = __builtin_nontemporal_load(((const v4f*)(z  + (size_t)row * EMB)) + c);
                z0v = __builtin_nontemporal_load(((const v4f*)(z0 + (size_t)row * EMB)) + c);
            } else {
                zv = (v4f)0.f; z0v = (v4f)0.f;
            }
            float p1 = w1.x * zv.x + w1.y * zv.y + w1.z * zv.z + w1.w * zv.w;
            float p2 = wa.x * zv.x + wa.y * zv.y + wa.z * zv.z + wa.w * zv.w;
            float p3 = wb.x * z0v.x + wb.y * z0v.y + wb.z * z0v.z + wb.w * z0v.w;
#pragma unroll
            for (int off = 16; off; off >>= 1) {
                p1 += __shfl_xor(p1, off, 64);
                p2 += __shfl_xor(p2, off, 64);
                p3 += __shfl_xor(p3, off, 64);
            }
            if (c == 0 && row < N) {
                v4f r; r.x = p1; r.y = p2; r.z = p3; r.w = 0.f;
                tab[row] = r;
            }
        }
    }

    grid.sync();

    // ---- phase 2a: reduce slots -> qmin, broadcast via LDS ----
    __shared__ int sq[5];
    {
        int t = threadIdx.x;
        int mm = min(min(slots[t], slots[t + 256]),
                     min(slots[t + 512], slots[t + 768]));
#pragma unroll
        for (int off = 32; off; off >>= 1)
            mm = min(mm, __shfl_xor(mm, off, 64));
        if ((t & 63) == 0) sq[t >> 6] = mm;
        __syncthreads();
        if (t == 0) sq[4] = min(min(sq[0], sq[1]), min(sq[2], sq[3]));
        __syncthreads();
    }
    const int qmin = sq[4];
    const float b0 = *bo;

    // ---- phase 2b: edge combine (same stride as 1a -> L2 re-hits) ----
    for (int v = gtid; v < nvec; v += ntot) {
        v4i a = r0[v];
        v4i b = r1[v];
        v4f r;
        r.x = tab[a.x].x + tab[b.x].y + tab[max(a.x, b.x) - qmin].z + b0;
        r.y = tab[a.y].x + tab[b.y].y + tab[max(a.y, b.y) - qmin].z + b0;
        r.z = tab[a.z].x + tab[b.z].y + tab[max(a.z, b.z) - qmin].z + b0;
        r.w = tab[a.w].x + tab[b.w].y + tab[max(a.w, b.w) - qmin].z + b0;
        __builtin_nontemporal_store(r, (v4f*)(out + ((size_t)v << 2)));
    }
    if (gtid < (E & 3)) {
        int e = (nvec << 2) + gtid;
        int a = ei[e], b = ei[e + E];
        out[e] = tab[a].x + tab[b].y + tab[max(a, b) - qmin].z + b0;
    }
}

extern "C" void kernel_launch(void* const* d_in, const int* in_sizes, int n_in,
                              void* d_out, int out_size, void* d_ws, size_t ws_size,
                              hipStream_t stream) {
    const float* z    = (const float*)d_in[0];
    const int*   ei   = (const int*)d_in[1];
    const float* z0   = (const float*)d_in[2];
    const float* Wq   = (const float*)d_in[3];
    const float* Wo   = (const float*)d_in[4];
    const float* bo   = (const float*)d_in[5];
    float* out = (float*)d_out;

    int N = in_sizes[0] / EMB;   // 100000
    int E = in_sizes[1] / 2;     // 1000000

    // Workspace layout: tab[N] (float4) | weff[256] | slots[1024]
    v4f*  tab   = (v4f*)d_ws;
    float* weff = (float*)(tab + N);
    int*  slots = (int*)(weff + EMB2);

    weff_kernel<<<1, EMB2, 0, stream>>>(Wq, Wo, weff);

    void* kargs[] = {
        (void*)&z, (void*)&z0, (void*)&ei, (void*)&E,
        (void*)&Wo, (void*)&weff, (void*)&bo,
        (void*)&tab, (void*)&N, (void*)&slots, (void*)&out
    };
    hipLaunchCooperativeKernel((const void*)fused_kernel,
                               dim3(GRID_BLOCKS), dim3(BLOCK_THREADS),
                               kargs, 0, stream);
}

// Round 5
// 211.208 us; speedup vs baseline: 1.1866x; 1.1866x over previous
//
#include <hip/hip_runtime.h>
#include <climits>

#define EMB 128
#define EMB2 256

typedef float v4f __attribute__((ext_vector_type(4)));
typedef int   v4i __attribute__((ext_vector_type(4)));

// ---------------------------------------------------------------------------
// Kernel 1 (1 block, 256 thr): weff[k] = sum_j Wo[0,128+j]*Wq[j,k]
// Thread 0 also initializes qmin = INT_MAX (runs before the scan kernel in
// stream order, so the atomicMin there is safe).
// ---------------------------------------------------------------------------
__global__ void weff_kernel(const float* __restrict__ Wq,
                            const float* __restrict__ Wo,
                            float* __restrict__ weff,
                            int* __restrict__ qmin) {
    int k = threadIdx.x;
    float acc = 0.f;
#pragma unroll 8
    for (int j = 0; j < EMB; ++j)
        acc += Wo[EMB + j] * Wq[j * EMB2 + k];
    weff[k] = acc;
    if (k == 0) *qmin = INT_MAX;
}

// ---------------------------------------------------------------------------
// Kernel 2 (one-shot wide grid, 6250 blocks x 256):
//  part A: qmin partial scan of ei (one int4 pair per thread) -> one
//          atomicMin per block.
//  part B: node dots, 4 rows/wave in 16-lane groups. Lane c of group g
//          loads row floats [4c,4c+4) and [64+4c,64+4c+4) from z and z0
//          (2x float4 each, 64 B/lane), then a 4-stage xor-shuffle reduce.
//          tab[i] = {Wo1.z[i], weffA.z[i], weffB.z0[i], 0}
// ---------------------------------------------------------------------------
__global__ void scan_dots_kernel(const float* __restrict__ z,
                                 const float* __restrict__ z0,
                                 const int* __restrict__ ei, int E,
                                 const float* __restrict__ Wo,
                                 const float* __restrict__ weff,
                                 v4f* __restrict__ tab, int N,
                                 int* __restrict__ qmin) {
    const int gtid = blockIdx.x * blockDim.x + threadIdx.x;

    // ---- part A: qmin scan (one int4-pair per thread) ----
    {
        int m = INT_MAX;
        const int nvec = E >> 2;
        if (gtid < nvec) {
            v4i a = ((const v4i*)ei)[gtid];
            v4i b = ((const v4i*)(ei + E))[gtid];
            int m0 = max(a.x, b.x), m1 = max(a.y, b.y);
            int m2 = max(a.z, b.z), m3 = max(a.w, b.w);
            m = min(min(m0, m1), min(m2, m3));
        }
        if (gtid < (E & 3)) {  // tail edges
            int e = (nvec << 2) + gtid;
            m = min(m, max(ei[e], ei[e + E]));
        }
#pragma unroll
        for (int off = 32; off; off >>= 1)
            m = min(m, __shfl_xor(m, off, 64));
        __shared__ int sm[4];
        if ((threadIdx.x & 63) == 0) sm[threadIdx.x >> 6] = m;
        __syncthreads();
        if (threadIdx.x == 0)
            atomicMin(qmin, min(min(sm[0], sm[1]), min(sm[2], sm[3])));
    }

    // ---- part B: node dots, 4 rows per wave ----
    const int wave = gtid >> 6;
    const int lane = gtid & 63;
    const int sub = lane >> 4;   // row within quad [0,4)
    const int c = lane & 15;     // float4 column group within 16-lane team
    const int row = wave * 4 + sub;
    if (row >= N) return;

    // weight slices for the two half-rows this lane covers
    v4f w1a = ((const v4f*)Wo)[c],        w1b = ((const v4f*)Wo)[16 + c];
    v4f waa = ((const v4f*)weff)[c],      wab = ((const v4f*)weff)[16 + c];
    v4f wba = ((const v4f*)weff)[32 + c], wbb = ((const v4f*)weff)[48 + c];

    const v4f* zr  = (const v4f*)(z  + (size_t)row * EMB);
    const v4f* z0r = (const v4f*)(z0 + (size_t)row * EMB);
    v4f za = __builtin_nontemporal_load(zr + c);
    v4f zb = __builtin_nontemporal_load(zr + 16 + c);
    v4f qa = __builtin_nontemporal_load(z0r + c);
    v4f qb = __builtin_nontemporal_load(z0r + 16 + c);

    float p1 = w1a.x * za.x + w1a.y * za.y + w1a.z * za.z + w1a.w * za.w
             + w1b.x * zb.x + w1b.y * zb.y + w1b.z * zb.z + w1b.w * zb.w;
    float p2 = waa.x * za.x + waa.y * za.y + waa.z * za.z + waa.w * za.w
             + wab.x * zb.x + wab.y * zb.y + wab.z * zb.z + wab.w * zb.w;
    float p3 = wba.x * qa.x + wba.y * qa.y + wba.z * qa.z + wba.w * qa.w
             + wbb.x * qb.x + wbb.y * qb.y + wbb.z * qb.z + wbb.w * qb.w;

#pragma unroll
    for (int off = 8; off; off >>= 1) {   // reduce within 16-lane team
        p1 += __shfl_xor(p1, off, 64);
        p2 += __shfl_xor(p2, off, 64);
        p3 += __shfl_xor(p3, off, 64);
    }
    if (c == 0) {
        v4f r; r.x = p1; r.y = p2; r.z = p3; r.w = 0.f;
        tab[row] = r;
    }
}

// ---------------------------------------------------------------------------
// Kernel 3: per-edge combine, 4 edges/thread via int4.
//   out[e] = tab[a].x + tab[b].y + tab[max(a,b)-qmin].z + bo
// tab (1.6 MB) is L2-resident; non-temporal store for out.
// ---------------------------------------------------------------------------
__global__ void edge_out_kernel(const int* __restrict__ ei,
                                const v4f* __restrict__ tab,
                                const int* __restrict__ qminp,
                                const float* __restrict__ bo,
                                float* __restrict__ out, int E) {
    int qmin = *qminp;
    float b0 = *bo;
    int t = blockIdx.x * blockDim.x + threadIdx.x;
    int e4 = t << 2;
    if (e4 + 3 < E) {
        v4i a = *(const v4i*)(ei + e4);
        v4i b = *(const v4i*)(ei + E + e4);
        v4f r;
        r.x = tab[a.x].x + tab[b.x].y + tab[max(a.x, b.x) - qmin].z + b0;
        r.y = tab[a.y].x + tab[b.y].y + tab[max(a.y, b.y) - qmin].z + b0;
        r.z = tab[a.z].x + tab[b.z].y + tab[max(a.z, b.z) - qmin].z + b0;
        r.w = tab[a.w].x + tab[b.w].y + tab[max(a.w, b.w) - qmin].z + b0;
        __builtin_nontemporal_store(r, (v4f*)(out + e4));
    } else {
        for (int e = e4; e < E; ++e) {
            int a = ei[e], b = ei[e + E];
            out[e] = tab[a].x + tab[b].y + tab[max(a, b) - qmin].z + b0;
        }
    }
}

extern "C" void kernel_launch(void* const* d_in, const int* in_sizes, int n_in,
                              void* d_out, int out_size, void* d_ws, size_t ws_size,
                              hipStream_t stream) {
    const float* z    = (const float*)d_in[0];
    const int*   ei   = (const int*)d_in[1];
    const float* z0   = (const float*)d_in[2];
    const float* Wq   = (const float*)d_in[3];
    const float* Wo   = (const float*)d_in[4];
    const float* bo   = (const float*)d_in[5];
    float* out = (float*)d_out;

    int N = in_sizes[0] / EMB;   // 100000
    int E = in_sizes[1] / 2;     // 1000000

    // Workspace layout: tab[N] (float4) | weff[256] | qmin (int)
    v4f*  tab   = (v4f*)d_ws;
    float* weff = (float*)(tab + N);
    int*  qmin  = (int*)(weff + EMB2);

    // 1: weff + qmin init (single tiny block)
    weff_kernel<<<1, EMB2, 0, stream>>>(Wq, Wo, weff, qmin);

    // 2: fused ei-scan (qmin) + node dots, one-shot wide grid.
    //    waves needed = ceil(N/4); blocks = ceil(waves/4). Also must cover
    //    E/4 threads for the scan: take the max.
    int wavesB = (N + 3) / 4;
    int blocksB = (wavesB + 3) / 4;
    int blocksScan = ((E + 3) / 4 + 255) / 256;
    int blocks2 = blocksB > blocksScan ? blocksB : blocksScan;
    scan_dots_kernel<<<blocks2, 256, 0, stream>>>(z, z0, ei, E, Wo, weff,
                                                  tab, N, qmin);

    // 3: per-edge combine, 4 edges/thread
    int blocksD = ((E + 3) / 4 + 255) / 256;
    edge_out_kernel<<<blocksD, 256, 0, stream>>>(ei, tab, qmin, bo, out, E);
}

// Round 6
// 160.787 us; speedup vs baseline: 1.5587x; 1.3136x over previous
//
#include <hip/hip_runtime.h>
#include <climits>

#define EMB 128
#define EMB2 256

typedef float v4f __attribute__((ext_vector_type(4)));
typedef int   v4i __attribute__((ext_vector_type(4)));

// ---------------------------------------------------------------------------
// Kernel AB (fused): block 0 computes weff[k] = sum_j Wo[0,128+j]*Wq[j,k];
// blocks 1..512 compute qmin = min_e max(ei[0,e], ei[1,e]) via unsigned
// atomicMin (qmin slot pre-initialized to 0xFFFFFFFF by hipMemsetAsync).
// NOTE: atomic count must NOT scale with grid (R4 lesson: 6250 same-line
// atomics serialized at ~29 cyc each = 76 us tail).
// ---------------------------------------------------------------------------
__global__ void prep_kernel(const float* __restrict__ Wq,
                            const float* __restrict__ Wo,
                            const int* __restrict__ ei, int E,
                            float* __restrict__ weff,
                            unsigned int* __restrict__ qmin) {
    if (blockIdx.x == 0) {
        int k = threadIdx.x;  // 256 threads
        float acc = 0.f;
#pragma unroll 8
        for (int j = 0; j < EMB; ++j)
            acc += Wo[EMB + j] * Wq[j * EMB2 + k];
        weff[k] = acc;
        return;
    }
    unsigned int m = 0xFFFFFFFFu;
    int nvec = E >> 2;
    int nthreads = (gridDim.x - 1) * blockDim.x;
    int tid = (blockIdx.x - 1) * blockDim.x + threadIdx.x;
    const v4i* r0 = (const v4i*)ei;
    const v4i* r1 = (const v4i*)(ei + E);
    for (int v = tid; v < nvec; v += nthreads) {
        v4i a = r0[v];
        v4i b = r1[v];
        unsigned m0 = (unsigned)max(a.x, b.x), m1 = (unsigned)max(a.y, b.y);
        unsigned m2 = (unsigned)max(a.z, b.z), m3 = (unsigned)max(a.w, b.w);
        m = min(m, min(min(m0, m1), min(m2, m3)));
    }
    if (blockIdx.x == 1 && threadIdx.x < (E & 3)) {  // tail
        int e = (nvec << 2) + threadIdx.x;
        m = min(m, (unsigned)max(ei[e], ei[e + E]));
    }
    for (int off = 32; off; off >>= 1) {
        unsigned o = (unsigned)__shfl_xor((int)m, off, 64);
        m = min(m, o);
    }
    __shared__ unsigned sm[4];
    int wid = threadIdx.x >> 6;
    if ((threadIdx.x & 63) == 0) sm[wid] = m;
    __syncthreads();
    if (threadIdx.x == 0) {
        unsigned r = min(min(sm[0], sm[1]), min(sm[2], sm[3]));
        atomicMin(qmin, r);
    }
}

// ---------------------------------------------------------------------------
// Kernel C: per-node dot products -> packed float4 table.
//   tab[i] = { Wo[0,0:128].z[i], weff[0:128].z[i], weff[128:256].z0[i], 0 }
// One-shot wide grid, 2 rows/wave (32 lanes x float4 = 512B/row), NT loads.
// No atomics, no loops: max TLP for the latency-sensitive shuffle reduce.
// ---------------------------------------------------------------------------
__global__ void node_dots_kernel(const float* __restrict__ z,
                                 const float* __restrict__ z0,
                                 const float* __restrict__ Wo,
                                 const float* __restrict__ weff,
                                 v4f* __restrict__ tab,
                                 int N) {
    int gtid = blockIdx.x * blockDim.x + threadIdx.x;
    int wave = gtid >> 6;
    int lane = gtid & 63;
    int sub = lane >> 5;   // which row of the pair
    int c = lane & 31;     // column group (4 floats)
    int row = wave * 2 + sub;
    if (row >= N) return;

    v4f w1 = ((const v4f*)Wo)[c];          // Wo[0, 4c:4c+4]
    v4f wa = ((const v4f*)weff)[c];        // weff[0:128]
    v4f wb = ((const v4f*)weff)[32 + c];   // weff[128:256]

    v4f zv  = __builtin_nontemporal_load(((const v4f*)(z  + (size_t)row * EMB)) + c);
    v4f z0v = __builtin_nontemporal_load(((const v4f*)(z0 + (size_t)row * EMB)) + c);

    float p1 = w1.x * zv.x + w1.y * zv.y + w1.z * zv.z + w1.w * zv.w;
    float p2 = wa.x * zv.x + wa.y * zv.y + wa.z * zv.z + wa.w * zv.w;
    float p3 = wb.x * z0v.x + wb.y * z0v.y + wb.z * z0v.z + wb.w * z0v.w;

#pragma unroll
    for (int off = 16; off; off >>= 1) {
        p1 += __shfl_xor(p1, off, 64);
        p2 += __shfl_xor(p2, off, 64);
        p3 += __shfl_xor(p3, off, 64);
    }
    if (c == 0) {
        v4f r; r.x = p1; r.y = p2; r.z = p3; r.w = 0.f;
        tab[row] = r;
    }
}

// ---------------------------------------------------------------------------
// Kernel D: per-edge combine, 4 edges/thread via int4.
//   out[e] = tab[a].x + tab[b].y + tab[max(a,b)-qmin].z + bo
// tab (1.6 MB) is L2-resident; non-temporal store for out.
// ---------------------------------------------------------------------------
__global__ void edge_out_kernel(const int* __restrict__ ei,
                                const v4f* __restrict__ tab,
                                const int* __restrict__ qminp,
                                const float* __restrict__ bo,
                                float* __restrict__ out, int E) {
    int qmin = *qminp;
    float b0 = *bo;
    int t = blockIdx.x * blockDim.x + threadIdx.x;
    int e4 = t << 2;
    if (e4 + 3 < E) {
        v4i a = *(const v4i*)(ei + e4);
        v4i b = *(const v4i*)(ei + E + e4);
        v4f r;
        r.x = tab[a.x].x + tab[b.x].y + tab[max(a.x, b.x) - qmin].z + b0;
        r.y = tab[a.y].x + tab[b.y].y + tab[max(a.y, b.y) - qmin].z + b0;
        r.z = tab[a.z].x + tab[b.z].y + tab[max(a.z, b.z) - qmin].z + b0;
        r.w = tab[a.w].x + tab[b.w].y + tab[max(a.w, b.w) - qmin].z + b0;
        __builtin_nontemporal_store(r, (v4f*)(out + e4));
    } else {
        for (int e = e4; e < E; ++e) {
            int a = ei[e], b = ei[e + E];
            out[e] = tab[a].x + tab[b].y + tab[max(a, b) - qmin].z + b0;
        }
    }
}

extern "C" void kernel_launch(void* const* d_in, const int* in_sizes, int n_in,
                              void* d_out, int out_size, void* d_ws, size_t ws_size,
                              hipStream_t stream) {
    const float* z    = (const float*)d_in[0];
    const int*   ei   = (const int*)d_in[1];
    const float* z0   = (const float*)d_in[2];
    const float* Wq   = (const float*)d_in[3];
    const float* Wo   = (const float*)d_in[4];
    const float* bo   = (const float*)d_in[5];
    float* out = (float*)d_out;

    int N = in_sizes[0] / EMB;   // 100000
    int E = in_sizes[1] / 2;     // 1000000

    // Workspace layout: tab[N] (float4, 16B-aligned) | weff[256] | qmin (u32)
    v4f* tab = (v4f*)d_ws;
    float* weff = (float*)(tab + N);
    unsigned int* qmin = (unsigned int*)(weff + EMB2);

    // Init qmin slot to 0xFFFFFFFF (async memset is graph-capturable)
    hipMemsetAsync(qmin, 0xFF, sizeof(unsigned int), stream);

    // AB: weff (block 0) + qmin reduction (blocks 1..512, 512 atomics total)
    prep_kernel<<<513, 256, 0, stream>>>(Wq, Wo, ei, E, weff, qmin);

    // C: per-node dots, one wave per row pair (4 waves/block), one-shot grid
    int pairs = (N + 1) / 2;
    int blocksC = (pairs + 3) / 4;
    node_dots_kernel<<<blocksC, 256, 0, stream>>>(z, z0, Wo, weff, tab, N);

    // D: per-edge combine, 4 edges/thread
    int threadsD = (E + 3) / 4;
    int blocksD = (threadsD + 255) / 256;
    edge_out_kernel<<<blocksD, 256, 0, stream>>>(ei, tab, (const int*)qmin, bo, out, E);
}

// Round 7
// 152.776 us; speedup vs baseline: 1.6404x; 1.0524x over previous
//
#include <hip/hip_runtime.h>
#include <climits>

#define EMB 128
#define EMB2 256
#define QBLOCKS 512   // number of qmin-scan blocks (fixed, small)

typedef float v4f __attribute__((ext_vector_type(4)));
typedef int   v4i __attribute__((ext_vector_type(4)));

// ---------------------------------------------------------------------------
// Kernel AB (fused): block 0 computes weff[k] = sum_j Wo[0,128+j]*Wq[j,k];
// blocks 1..QBLOCKS compute per-block qmin partials -> slots[b-1].
// No atomics, no init dependency (every slot written unconditionally).
// (R4 lesson: same-line atomics must not scale with grid; here: zero atomics.)
// ---------------------------------------------------------------------------
__global__ void prep_kernel(const float* __restrict__ Wq,
                            const float* __restrict__ Wo,
                            const int* __restrict__ ei, int E,
                            float* __restrict__ weff,
                            int* __restrict__ slots) {
    if (blockIdx.x == 0) {
        int k = threadIdx.x;  // 256 threads
        float acc = 0.f;
#pragma unroll 8
        for (int j = 0; j < EMB; ++j)
            acc += Wo[EMB + j] * Wq[j * EMB2 + k];
        weff[k] = acc;
        return;
    }
    int m = INT_MAX;
    int nvec = E >> 2;
    int nthreads = QBLOCKS * blockDim.x;
    int tid = (blockIdx.x - 1) * blockDim.x + threadIdx.x;
    const v4i* r0 = (const v4i*)ei;
    const v4i* r1 = (const v4i*)(ei + E);
    for (int v = tid; v < nvec; v += nthreads) {
        v4i a = r0[v];
        v4i b = r1[v];
        int m0 = max(a.x, b.x), m1 = max(a.y, b.y);
        int m2 = max(a.z, b.z), m3 = max(a.w, b.w);
        m = min(m, min(min(m0, m1), min(m2, m3)));
    }
    if (blockIdx.x == 1 && threadIdx.x < (E & 3)) {  // tail edges
        int e = (nvec << 2) + threadIdx.x;
        m = min(m, max(ei[e], ei[e + E]));
    }
#pragma unroll
    for (int off = 32; off; off >>= 1)
        m = min(m, __shfl_xor(m, off, 64));
    __shared__ int sm[4];
    int wid = threadIdx.x >> 6;
    if ((threadIdx.x & 63) == 0) sm[wid] = m;
    __syncthreads();
    if (threadIdx.x == 0)
        slots[blockIdx.x - 1] = min(min(sm[0], sm[1]), min(sm[2], sm[3]));
}

// ---------------------------------------------------------------------------
// Kernel C: per-node dot products -> packed float4 table.
//   tab[i] = { Wo[0,0:128].z[i], weff[0:128].z[i], weff[128:256].z0[i], 0 }
// One-shot wide grid, 2 rows/wave (32 lanes x float4 = 512B/row), NT loads.
// No atomics, no loops: max TLP for the latency-sensitive shuffle reduce.
// ---------------------------------------------------------------------------
__global__ void node_dots_kernel(const float* __restrict__ z,
                                 const float* __restrict__ z0,
                                 const float* __restrict__ Wo,
                                 const float* __restrict__ weff,
                                 v4f* __restrict__ tab,
                                 int N) {
    int gtid = blockIdx.x * blockDim.x + threadIdx.x;
    int wave = gtid >> 6;
    int lane = gtid & 63;
    int sub = lane >> 5;   // which row of the pair
    int c = lane & 31;     // column group (4 floats)
    int row = wave * 2 + sub;
    if (row >= N) return;

    v4f w1 = ((const v4f*)Wo)[c];          // Wo[0, 4c:4c+4]
    v4f wa = ((const v4f*)weff)[c];        // weff[0:128]
    v4f wb = ((const v4f*)weff)[32 + c];   // weff[128:256]

    v4f zv  = __builtin_nontemporal_load(((const v4f*)(z  + (size_t)row * EMB)) + c);
    v4f z0v = __builtin_nontemporal_load(((const v4f*)(z0 + (size_t)row * EMB)) + c);

    float p1 = w1.x * zv.x + w1.y * zv.y + w1.z * zv.z + w1.w * zv.w;
    float p2 = wa.x * zv.x + wa.y * zv.y + wa.z * zv.z + wa.w * zv.w;
    float p3 = wb.x * z0v.x + wb.y * z0v.y + wb.z * z0v.z + wb.w * z0v.w;

#pragma unroll
    for (int off = 16; off; off >>= 1) {
        p1 += __shfl_xor(p1, off, 64);
        p2 += __shfl_xor(p2, off, 64);
        p3 += __shfl_xor(p3, off, 64);
    }
    if (c == 0) {
        v4f r; r.x = p1; r.y = p2; r.z = p3; r.w = 0.f;
        tab[row] = r;
    }
}

// ---------------------------------------------------------------------------
// Kernel D: per-edge combine, 4 edges/thread via int4.
// Each block first reduces the L2-resident slots[512] -> qmin (no atomic,
// no extra dispatch), then:
//   out[e] = tab[a].x + tab[b].y + tab[max(a,b)-qmin].z + bo
// ---------------------------------------------------------------------------
__global__ void edge_out_kernel(const int* __restrict__ ei,
                                const v4f* __restrict__ tab,
                                const int* __restrict__ slots,
                                const float* __restrict__ bo,
                                float* __restrict__ out, int E) {
    // block-local qmin reduce of slots[0..511]
    __shared__ int sq[5];
    {
        int t = threadIdx.x;  // 256 threads
        int mm = min(slots[t], slots[t + 256]);
#pragma unroll
        for (int off = 32; off; off >>= 1)
            mm = min(mm, __shfl_xor(mm, off, 64));
        if ((t & 63) == 0) sq[t >> 6] = mm;
        __syncthreads();
        if (t == 0) sq[4] = min(min(sq[0], sq[1]), min(sq[2], sq[3]));
        __syncthreads();
    }
    const int qmin = sq[4];
    const float b0 = *bo;

    int t = blockIdx.x * blockDim.x + threadIdx.x;
    int e4 = t << 2;
    if (e4 + 3 < E) {
        v4i a = *(const v4i*)(ei + e4);
        v4i b = *(const v4i*)(ei + E + e4);
        v4f r;
        r.x = tab[a.x].x + tab[b.x].y + tab[max(a.x, b.x) - qmin].z + b0;
        r.y = tab[a.y].x + tab[b.y].y + tab[max(a.y, b.y) - qmin].z + b0;
        r.z = tab[a.z].x + tab[b.z].y + tab[max(a.z, b.z) - qmin].z + b0;
        r.w = tab[a.w].x + tab[b.w].y + tab[max(a.w, b.w) - qmin].z + b0;
        __builtin_nontemporal_store(r, (v4f*)(out + e4));
    } else {
        for (int e = e4; e < E; ++e) {
            int a = ei[e], b = ei[e + E];
            out[e] = tab[a].x + tab[b].y + tab[max(a, b) - qmin].z + b0;
        }
    }
}

extern "C" void kernel_launch(void* const* d_in, const int* in_sizes, int n_in,
                              void* d_out, int out_size, void* d_ws, size_t ws_size,
                              hipStream_t stream) {
    const float* z    = (const float*)d_in[0];
    const int*   ei   = (const int*)d_in[1];
    const float* z0   = (const float*)d_in[2];
    const float* Wq   = (const float*)d_in[3];
    const float* Wo   = (const float*)d_in[4];
    const float* bo   = (const float*)d_in[5];
    float* out = (float*)d_out;

    int N = in_sizes[0] / EMB;   // 100000
    int E = in_sizes[1] / 2;     // 1000000

    // Workspace layout: tab[N] (float4, 16B-aligned) | weff[256] | slots[512]
    v4f* tab = (v4f*)d_ws;
    float* weff = (float*)(tab + N);
    int* slots = (int*)(weff + EMB2);

    // AB: weff (block 0) + qmin partials -> slots (blocks 1..512)
    prep_kernel<<<1 + QBLOCKS, 256, 0, stream>>>(Wq, Wo, ei, E, weff, slots);

    // C: per-node dots, one wave per row pair (4 waves/block), one-shot grid
    int pairs = (N + 1) / 2;
    int blocksC = (pairs + 3) / 4;
    node_dots_kernel<<<blocksC, 256, 0, stream>>>(z, z0, Wo, weff, tab, N);

    // D: per-edge combine, 4 edges/thread; qmin reduced per-block from slots
    int threadsD = (E + 3) / 4;
    int blocksD = (threadsD + 255) / 256;
    edge_out_kernel<<<blocksD, 256, 0, stream>>>(ei, tab, slots, bo, out, E);
}